// Round 1
// baseline (43.081 us; speedup 1.0000x reference)
//
#include <hip/hip_runtime.h>

#define GH 16
#define GW 16
#define GD 8
#define GC 12
#define H 1024
#define W 1024
#define NB 2

// ---------------------------------------------------------------------------
// Tiny pre-pass: transpose bilateral_grid [b][c][gk][gi][gj] (2,12,8,16,16)
// into gridT [b][gi][gj][gk][c] so the 12 channels are contiguous (float4-able).
// 49152 elements total (196 KB) -> lives in d_ws, stays L2-resident.
// ---------------------------------------------------------------------------
__global__ __launch_bounds__(256) void transpose_grid_k(const float* __restrict__ src,
                                                        float* __restrict__ dst) {
  int t = blockIdx.x * 256 + threadIdx.x;
  if (t >= NB * GH * GW * GD * GC) return;
  int c = t % GC;
  int r = t / GC;
  int gk = r % GD; r /= GD;
  int gj = r % GW; r /= GW;
  int gi = r % GH;
  int b  = r / GH;
  dst[t] = src[(((b * GC + c) * GD + gk) * GH + gi) * GW + gj];
}

// ---------------------------------------------------------------------------
// Main slice kernel. One thread = 4 consecutive j-pixels (quad-aligned, so all
// 4 share the same (gi,gj) cell pair: cell boundaries fall on j%32==0).
// TR=true: grid is the transposed layout above (float4 loads).
// TR=false: fallback, direct indexing into the original layout (scalar loads).
// ---------------------------------------------------------------------------
template <bool TR>
__global__ __launch_bounds__(256) void slice_k(const float* __restrict__ grid,
                                               const float* __restrict__ guide,
                                               float* __restrict__ out) {
  const int tid = blockIdx.x * 256 + threadIdx.x;   // 524288 threads total
  const int j0 = (tid & 255) << 2;                  // quad start along j
  const int ri = tid >> 8;
  const int i  = ri & (H - 1);
  const int b  = ri >> 10;

  const float4 g4 = *reinterpret_cast<const float4*>(guide + ((b << 20) | (i << 10) | j0));
  const float gv[4] = {g4.x, g4.y, g4.z, g4.w};

  // --- i weights (shared by the whole thread) ---
  // gif = (i+0.5)*(GH/H); gi0 = floor(gif-0.5); wi0 = 1-t, wi1 = t (exact per ref)
  float fi  = (i + 0.5f) * (1.0f / 64.0f) - 0.5f;
  float fif = floorf(fi);
  int   gi0 = (int)fif;
  float ti  = fi - fif;
  float wi0 = 1.0f - ti, wi1 = ti;
  int gi0c = gi0 < 0 ? 0 : gi0;
  int gi1c = (gi0 + 1 > GH - 1) ? GH - 1 : gi0 + 1;

  // --- j cell (shared across the quad; per-pixel fractional t) ---
  float fj  = (j0 + 0.5f) * (1.0f / 64.0f) - 0.5f;
  float fjf = floorf(fj);
  int   gj0 = (int)fjf;
  float tj0 = fj - fjf;
  int gj0c = gj0 < 0 ? 0 : gj0;
  int gj1c = (gj0 + 1 > GW - 1) ? GW - 1 : gj0 + 1;

  float acc[4][GC];
#pragma unroll
  for (int p = 0; p < 4; ++p)
#pragma unroll
    for (int c = 0; c < GC; ++c) acc[p][c] = 0.0f;

#pragma unroll
  for (int p = 0; p < 4; ++p) {
    float tj  = tj0 + p * (1.0f / 64.0f);
    float wj0 = 1.0f - tj, wj1 = tj;

    // --- k weights (smoothed lerp, per reference) ---
    float gkf = gv[p] * (float)GD;
    float fk  = gkf - 0.5f;
    float fkf = floorf(fk);
    int   gk0 = (int)fkf;
    float tk  = fk - fkf;
    float wk0 = fmaxf(1.0f - sqrtf(tk * tk + 1e-8f), 0.0f);
    float uk  = 1.0f - tk;
    float wk1 = fmaxf(1.0f - sqrtf(uk * uk + 1e-8f), 0.0f);
    int gk0c = gk0 < 0 ? 0 : gk0;
    int gk1c = (gk0 + 1 > GD - 1) ? GD - 1 : gk0 + 1;

    const float cw[4]  = {wi0 * wj0, wi0 * wj1, wi1 * wj0, wi1 * wj1};
    const int   cia[4] = {gi0c, gi0c, gi1c, gi1c};
    const int   cja[4] = {gj0c, gj1c, gj0c, gj1c};

#pragma unroll
    for (int cell = 0; cell < 4; ++cell) {
      float a0 = cw[cell] * wk0;
      float a1 = cw[cell] * wk1;
      if (TR) {
        const float* cb = grid + b * (GH * GW * GD * GC)
                               + (cia[cell] * GW + cja[cell]) * (GD * GC);
        const float4* r0 = reinterpret_cast<const float4*>(cb + gk0c * GC);
        const float4* r1 = reinterpret_cast<const float4*>(cb + gk1c * GC);
#pragma unroll
        for (int q = 0; q < 3; ++q) {
          float4 v0 = r0[q];
          float4 v1 = r1[q];
          acc[p][q * 4 + 0] += a0 * v0.x + a1 * v1.x;
          acc[p][q * 4 + 1] += a0 * v0.y + a1 * v1.y;
          acc[p][q * 4 + 2] += a0 * v0.z + a1 * v1.z;
          acc[p][q * 4 + 3] += a0 * v0.w + a1 * v1.w;
        }
      } else {
        int off = cia[cell] * GW + cja[cell];
#pragma unroll
        for (int c = 0; c < GC; ++c) {
          const float* cp = grid + (size_t)((b * GC + c) * GD) * (GH * GW) + off;
          acc[p][c] += a0 * cp[gk0c * GH * GW] + a1 * cp[gk1c * GH * GW];
        }
      }
    }
  }

  // --- store: out[b][c][i][j0..j0+3], float4 per channel ---
  float* ob = out + ((b * GC) << 20) + (i << 10) + j0;
#pragma unroll
  for (int c = 0; c < GC; ++c) {
    float4 v = make_float4(acc[0][c], acc[1][c], acc[2][c], acc[3][c]);
    *reinterpret_cast<float4*>(ob + (c << 20)) = v;
  }
}

extern "C" void kernel_launch(void* const* d_in, const int* in_sizes, int n_in,
                              void* d_out, int out_size, void* d_ws, size_t ws_size,
                              hipStream_t stream) {
  const float* grid  = (const float*)d_in[0];   // (2,12,8,16,16) fp32
  const float* guide = (const float*)d_in[1];   // (2,1,1024,1024) fp32
  float* out = (float*)d_out;                   // (2,12,1024,1024) fp32

  constexpr size_t GRID_ELEMS = (size_t)NB * GH * GW * GD * GC;  // 49152
  const int nthreads = NB * H * (W / 4);        // 524288
  const int nblocks  = nthreads / 256;          // 2048

  if (ws_size >= GRID_ELEMS * sizeof(float)) {
    float* gridT = (float*)d_ws;
    transpose_grid_k<<<(int)((GRID_ELEMS + 255) / 256), 256, 0, stream>>>(grid, gridT);
    slice_k<true><<<nblocks, 256, 0, stream>>>(gridT, guide, out);
  } else {
    slice_k<false><<<nblocks, 256, 0, stream>>>(grid, guide, out);
  }
}

// Round 2
// 28.179 us; speedup vs baseline: 1.5289x; 1.5289x over previous
//
#include <hip/hip_runtime.h>

#define GH 16
#define GW 16
#define GD 8
#define GC 12
#define H 1024
#define W 1024
#define NB 2

// LDS layout for the i-pre-reduced grid slab gridI[gj][gk][c]:
// gk stride padded 12->20 floats (80 B: spreads the 8 gk rows across all 32
// banks, stays 16B-aligned); gj stride = 8*20+4 = 164 floats (adds a 4-bank
// rotation per gj so neighboring j-cells don't collide).
#define GKS 20
#define GJS (GD * GKS + 4)          // 164 floats
#define LDS_FLOATS (GW * GJS)       // 2624 floats = 10496 B

__global__ __launch_bounds__(256) void slice_fused_k(const float* __restrict__ grid,
                                                     const float* __restrict__ guide,
                                                     float* __restrict__ out) {
  __shared__ float gI[LDS_FLOATS];

  const int tid = threadIdx.x;
  const int bi  = blockIdx.x;          // b*1024 + i : one block per output row
  const int i   = bi & (H - 1);
  const int b   = bi >> 10;

  // --- i weights (uniform per block) ---
  // gif = (i+0.5)/64; gi0 = floor(gif-0.5); wi0 = 1-t, wi1 = t (exact per ref)
  float fi  = (i + 0.5f) * (1.0f / 64.0f) - 0.5f;
  float fif = floorf(fi);
  int   gi0 = (int)fif;
  float ti  = fi - fif;
  float wi0 = 1.0f - ti, wi1 = ti;
  int gi0c = gi0 < 0 ? 0 : gi0;
  int gi1c = (gi0 + 1 > GH - 1) ? GH - 1 : gi0 + 1;

  // --- Phase 1: build gI[gj][gk][c] = wi0*G[b][c][gk][gi0c][gj] + wi1*G[b][c][gk][gi1c][gj]
  // from the ORIGINAL layout (b,c,gk,gi,gj); float4 along gj (contiguous).
  // 384 float4-slots: slot = (c*GD+gk)*4 + gq, gj = 4*gq + m.
  const float* gb = grid + (size_t)b * (GC * GD * GH * GW);
  for (int s = tid; s < GC * GD * (GW / 4); s += 256) {
    int gq = s & 3;
    int ck = s >> 2;                   // c*8 + gk
    const float* rowbase = gb + (ck << 8);   // (c*8+gk)*256
    float4 v0 = *reinterpret_cast<const float4*>(rowbase + gi0c * GW + gq * 4);
    float4 v1 = *reinterpret_cast<const float4*>(rowbase + gi1c * GW + gq * 4);
    int gk = ck & 7;
    int c  = ck >> 3;
    int la = (gq * 4) * GJS + gk * GKS + c;
    gI[la + 0 * GJS] = wi0 * v0.x + wi1 * v1.x;
    gI[la + 1 * GJS] = wi0 * v0.y + wi1 * v1.y;
    gI[la + 2 * GJS] = wi0 * v0.z + wi1 * v1.z;
    gI[la + 3 * GJS] = wi0 * v0.w + wi1 * v1.w;
  }
  __syncthreads();

  // --- Phase 2: each thread = 4 consecutive j-pixels (quad never straddles a
  // j-cell: boundaries at j%64==32). 12 ds_read_b128 per pixel.
  const int j0 = tid << 2;
  const float4 g4 = *reinterpret_cast<const float4*>(
      guide + ((size_t)b << 20) + (i << 10) + j0);
  const float gv[4] = {g4.x, g4.y, g4.z, g4.w};

  float fj  = (j0 + 0.5f) * (1.0f / 64.0f) - 0.5f;
  float fjf = floorf(fj);
  int   gj0 = (int)fjf;
  float tj0 = fj - fjf;
  int gj0c = gj0 < 0 ? 0 : gj0;
  int gj1c = (gj0 + 1 > GW - 1) ? GW - 1 : gj0 + 1;
  const float* rj0 = gI + gj0c * GJS;
  const float* rj1 = gI + gj1c * GJS;

  float acc[4][GC];

#pragma unroll
  for (int p = 0; p < 4; ++p) {
    float tj  = tj0 + p * (1.0f / 64.0f);
    float wj0 = 1.0f - tj, wj1 = tj;

    // k weights (smoothed lerp, exact per reference)
    float fk  = gv[p] * (float)GD - 0.5f;
    float fkf = floorf(fk);
    int   gk0 = (int)fkf;
    float tk  = fk - fkf;
    float wk0 = fmaxf(1.0f - sqrtf(tk * tk + 1e-8f), 0.0f);
    float uk  = 1.0f - tk;
    float wk1 = fmaxf(1.0f - sqrtf(uk * uk + 1e-8f), 0.0f);
    int gk0c = gk0 < 0 ? 0 : gk0;
    int gk1c = (gk0 + 1 > GD - 1) ? GD - 1 : gk0 + 1;

    float w00 = wj0 * wk0, w01 = wj0 * wk1;
    float w10 = wj1 * wk0, w11 = wj1 * wk1;

    const float4* r00 = reinterpret_cast<const float4*>(rj0 + gk0c * GKS);
    const float4* r01 = reinterpret_cast<const float4*>(rj0 + gk1c * GKS);
    const float4* r10 = reinterpret_cast<const float4*>(rj1 + gk0c * GKS);
    const float4* r11 = reinterpret_cast<const float4*>(rj1 + gk1c * GKS);

#pragma unroll
    for (int q = 0; q < 3; ++q) {
      float4 a = r00[q], bb = r01[q], cc = r10[q], dd = r11[q];
      acc[p][q * 4 + 0] = w00 * a.x + w01 * bb.x + w10 * cc.x + w11 * dd.x;
      acc[p][q * 4 + 1] = w00 * a.y + w01 * bb.y + w10 * cc.y + w11 * dd.y;
      acc[p][q * 4 + 2] = w00 * a.z + w01 * bb.z + w10 * cc.z + w11 * dd.z;
      acc[p][q * 4 + 3] = w00 * a.w + w01 * bb.w + w10 * cc.w + w11 * dd.w;
    }
  }

  // --- store: out[b][c][i][j0..j0+3], one float4 per channel ---
  float* ob = out + (((size_t)b * GC) << 20) + (i << 10) + j0;
#pragma unroll
  for (int c = 0; c < GC; ++c) {
    float4 v = make_float4(acc[0][c], acc[1][c], acc[2][c], acc[3][c]);
    *reinterpret_cast<float4*>(ob + ((size_t)c << 20)) = v;
  }
}

extern "C" void kernel_launch(void* const* d_in, const int* in_sizes, int n_in,
                              void* d_out, int out_size, void* d_ws, size_t ws_size,
                              hipStream_t stream) {
  const float* grid  = (const float*)d_in[0];   // (2,12,8,16,16) fp32
  const float* guide = (const float*)d_in[1];   // (2,1,1024,1024) fp32
  float* out = (float*)d_out;                   // (2,12,1024,1024) fp32

  const int nblocks = NB * H;                   // one block per (b, i) row
  slice_fused_k<<<nblocks, 256, 0, stream>>>(grid, guide, out);
}

// Round 3
// 25.548 us; speedup vs baseline: 1.6863x; 1.1030x over previous
//
#include <hip/hip_runtime.h>
#include <hip/hip_fp16.h>

#define GH 16
#define GW 16
#define GD 8
#define GC 12
#define H 1024
#define W 1024
#define NB 2

// LDS slab: i-pre-reduced grid, fp16, k-PAIR records.
// gP[gj][r][0..23]: halfs [0..11] = row gk=r channels 0..11,
//                   halfs [12..23] = row gk=r+1 channels 0..11.  r in [0,6].
// Pair record = 48 B, starts 16B-aligned (24 halfs); gj stride padded to 176
// halfs (352 B, multiple of 16 B) so every b128 stays aligned and gj-groups
// rotate banks.
#define GPR 24                    // halfs per pair record
#define NPAIR (GD - 1)            // 7
#define GJS_H (NPAIR * GPR + 8)   // 176 halfs per gj
#define LDS_HALFS (GW * GJS_H)    // 2816 halfs = 5632 B

__device__ inline float2 h2f(unsigned u) {
  __half2 h;
  *reinterpret_cast<unsigned*>(&h) = u;
  return __half22float2(h);
}

// Read one 48B pair record (rows r, r+1 for one gj) and accumulate:
// acc[c] += b0 * row_r[c] + b1 * row_{r+1}[c]
__device__ inline void accum_pair(const __half* __restrict__ gI, int off,
                                  float b0, float b1, float* __restrict__ acc) {
  uint4 q0 = *reinterpret_cast<const uint4*>(gI + off);        // r: c0..7
  uint4 q1 = *reinterpret_cast<const uint4*>(gI + off + 8);    // r: c8..11 | r+1: c0..3
  uint4 q2 = *reinterpret_cast<const uint4*>(gI + off + 16);   // r+1: c4..11
  float2 f;
  f = h2f(q0.x); acc[0]  += b0 * f.x; acc[1]  += b0 * f.y;
  f = h2f(q0.y); acc[2]  += b0 * f.x; acc[3]  += b0 * f.y;
  f = h2f(q0.z); acc[4]  += b0 * f.x; acc[5]  += b0 * f.y;
  f = h2f(q0.w); acc[6]  += b0 * f.x; acc[7]  += b0 * f.y;
  f = h2f(q1.x); acc[8]  += b0 * f.x; acc[9]  += b0 * f.y;
  f = h2f(q1.y); acc[10] += b0 * f.x; acc[11] += b0 * f.y;
  f = h2f(q1.z); acc[0]  += b1 * f.x; acc[1]  += b1 * f.y;
  f = h2f(q1.w); acc[2]  += b1 * f.x; acc[3]  += b1 * f.y;
  f = h2f(q2.x); acc[4]  += b1 * f.x; acc[5]  += b1 * f.y;
  f = h2f(q2.y); acc[6]  += b1 * f.x; acc[7]  += b1 * f.y;
  f = h2f(q2.z); acc[8]  += b1 * f.x; acc[9]  += b1 * f.y;
  f = h2f(q2.w); acc[10] += b1 * f.x; acc[11] += b1 * f.y;
}

__global__ __launch_bounds__(256, 4) void slice_fused_k(const float* __restrict__ grid,
                                                        const float* __restrict__ guide,
                                                        float* __restrict__ out) {
  __shared__ __half gI[LDS_HALFS];

  const int tid = threadIdx.x;
  const int bi  = blockIdx.x;          // b*1024 + i : one block per output row
  const int i   = bi & (H - 1);
  const int b   = bi >> 10;

  // --- i weights (uniform per block): gi0 = floor((i+0.5)/64 - 0.5) ---
  float fi  = (i + 0.5f) * (1.0f / 64.0f) - 0.5f;
  float fif = floorf(fi);
  int   gi0 = (int)fif;
  float ti  = fi - fif;
  float wi0 = 1.0f - ti, wi1 = ti;
  int gi0c = gi0 < 0 ? 0 : gi0;
  int gi1c = (gi0 + 1 > GH - 1) ? GH - 1 : gi0 + 1;

  // --- Phase 1: i-lerp the grid into the fp16 pair slab.
  // Source layout (b,c,gk,gi,gj); float4 along gj. Each value lands in up to
  // two pair records (as row-low of pair gk, as row-high of pair gk-1).
  const float* gb = grid + (size_t)b * (GC * GD * GH * GW);
  for (int s = tid; s < GC * GD * (GW / 4); s += 256) {
    int gq = s & 3;                    // gj quad
    int ck = s >> 2;                   // c*8 + gk
    int gk = ck & 7;
    int c  = ck >> 3;
    const float* rowbase = gb + (ck << 8);
    float4 v0 = *reinterpret_cast<const float4*>(rowbase + gi0c * GW + gq * 4);
    float4 v1 = *reinterpret_cast<const float4*>(rowbase + gi1c * GW + gq * 4);
    float vals[4] = {wi0 * v0.x + wi1 * v1.x, wi0 * v0.y + wi1 * v1.y,
                     wi0 * v0.z + wi1 * v1.z, wi0 * v0.w + wi1 * v1.w};
#pragma unroll
    for (int m = 0; m < 4; ++m) {
      __half hv = __float2half(vals[m]);
      int base = (gq * 4 + m) * GJS_H;
      if (gk < GD - 1) gI[base + gk * GPR + c] = hv;            // row-low of pair gk
      if (gk > 0)      gI[base + (gk - 1) * GPR + 12 + c] = hv; // row-high of pair gk-1
    }
  }
  __syncthreads();

  // --- Phase 2: one thread = 4 consecutive j-pixels (quad never straddles a
  // j-cell). 6 ds_read_b128 per pixel.
  const int j0 = tid << 2;
  const float4 g4 = *reinterpret_cast<const float4*>(
      guide + ((size_t)b << 20) + (i << 10) + j0);
  const float gv[4] = {g4.x, g4.y, g4.z, g4.w};

  float fj  = (j0 + 0.5f) * (1.0f / 64.0f) - 0.5f;
  float fjf = floorf(fj);
  int   gj0 = (int)fjf;
  float tj0 = fj - fjf;
  int gj0c = gj0 < 0 ? 0 : gj0;
  int gj1c = (gj0 + 1 > GW - 1) ? GW - 1 : gj0 + 1;
  const int rj0 = gj0c * GJS_H;
  const int rj1 = gj1c * GJS_H;

  float acc[4][GC];
#pragma unroll
  for (int p = 0; p < 4; ++p)
#pragma unroll
    for (int c = 0; c < GC; ++c) acc[p][c] = 0.0f;

#pragma unroll
  for (int p = 0; p < 4; ++p) {
    float tj  = tj0 + p * (1.0f / 64.0f);
    float wj0 = 1.0f - tj, wj1 = tj;

    // k weights (smoothed lerp, exact per reference)
    float fk  = gv[p] * (float)GD - 0.5f;
    float fkf = floorf(fk);
    int   gk0 = (int)fkf;                  // in [-1, 7]
    float tk  = fk - fkf;
    float wk0 = fmaxf(1.0f - sqrtf(tk * tk + 1e-8f), 0.0f);
    float uk  = 1.0f - tk;
    float wk1 = fmaxf(1.0f - sqrtf(uk * uk + 1e-8f), 0.0f);

    // clamp folded into pair weights: pair r covers rows (r, r+1)
    bool lo = gk0 < 0, hi = gk0 > GD - 2;
    int  r  = lo ? 0 : (hi ? GD - 2 : gk0);
    float a0 = lo ? wk0 + wk1 : (hi ? 0.0f : wk0);
    float a1 = hi ? wk0 + wk1 : (lo ? 0.0f : wk1);

    int off = r * GPR;
    accum_pair(gI, rj0 + off, wj0 * a0, wj0 * a1, acc[p]);
    accum_pair(gI, rj1 + off, wj1 * a0, wj1 * a1, acc[p]);
  }

  // --- store: out[b][c][i][j0..j0+3], one float4 per channel ---
  float* ob = out + (((size_t)b * GC) << 20) + (i << 10) + j0;
#pragma unroll
  for (int c = 0; c < GC; ++c) {
    float4 v = make_float4(acc[0][c], acc[1][c], acc[2][c], acc[3][c]);
    *reinterpret_cast<float4*>(ob + ((size_t)c << 20)) = v;
  }
}

extern "C" void kernel_launch(void* const* d_in, const int* in_sizes, int n_in,
                              void* d_out, int out_size, void* d_ws, size_t ws_size,
                              hipStream_t stream) {
  const float* grid  = (const float*)d_in[0];   // (2,12,8,16,16) fp32
  const float* guide = (const float*)d_in[1];   // (2,1,1024,1024) fp32
  float* out = (float*)d_out;                   // (2,12,1024,1024) fp32

  const int nblocks = NB * H;                   // one block per (b, i) row
  slice_fused_k<<<nblocks, 256, 0, stream>>>(grid, guide, out);
}

// Round 4
// 25.029 us; speedup vs baseline: 1.7213x; 1.0208x over previous
//
#include <hip/hip_runtime.h>
#include <hip/hip_fp16.h>

#define GH 16
#define GW 16
#define GD 8
#define GC 12
#define H 1024
#define W 1024
#define NB 2

// LDS slab: i-pre-reduced grid, fp16, k-PAIR records.
// gI[gj][r][0..23]: halfs [0..11] = row gk=r channels 0..11,
//                   halfs [12..23] = row gk=r+1 channels 0..11.  r in [0,6].
// Pair record = 48 B, 16B-aligned; gj stride 176 halfs (352 B) rotates banks
// by 24 per gj so the per-r bank sets (disjoint within a gj) rarely collide
// across the 4 gj-groups of a wave.
#define GPR 24                    // halfs per pair record
#define NPAIR (GD - 1)            // 7
#define GJS_H (NPAIR * GPR + 8)   // 176 halfs per gj
#define LDS_HALFS (GW * GJS_H)    // 2816 halfs = 5632 B

// Read one 48B pair record (rows r, r+1 for one gj) and accumulate into 6
// half2 channel-pair accumulators: acc[t] += b0*row_r[t] + b1*row_{r+1}[t].
// 3 ds_read_b128 + 12 v_pk_fma_f16, zero unpacking.
__device__ inline void accum_rec(const __half* __restrict__ gI, int off,
                                 __half2 b0, __half2 b1, __half2* __restrict__ acc) {
  union U { uint4 u; __half2 h[4]; };
  const uint4* p = reinterpret_cast<const uint4*>(gI + off);
  U qa, qb, qc;
  qa.u = p[0];   // row r: ch pairs 0..3
  qb.u = p[1];   // row r: ch pairs 4..5 | row r+1: ch pairs 0..1
  qc.u = p[2];   // row r+1: ch pairs 2..5
  acc[0] = __hfma2(b0, qa.h[0], acc[0]);
  acc[1] = __hfma2(b0, qa.h[1], acc[1]);
  acc[2] = __hfma2(b0, qa.h[2], acc[2]);
  acc[3] = __hfma2(b0, qa.h[3], acc[3]);
  acc[4] = __hfma2(b0, qb.h[0], acc[4]);
  acc[5] = __hfma2(b0, qb.h[1], acc[5]);
  acc[0] = __hfma2(b1, qb.h[2], acc[0]);
  acc[1] = __hfma2(b1, qb.h[3], acc[1]);
  acc[2] = __hfma2(b1, qc.h[0], acc[2]);
  acc[3] = __hfma2(b1, qc.h[1], acc[3]);
  acc[4] = __hfma2(b1, qc.h[2], acc[4]);
  acc[5] = __hfma2(b1, qc.h[3], acc[5]);
}

__global__ __launch_bounds__(256, 4) void slice_fused_k(const float* __restrict__ grid,
                                                        const float* __restrict__ guide,
                                                        float* __restrict__ out) {
  __shared__ __half gI[LDS_HALFS];

  const int tid = threadIdx.x;
  const int bi  = blockIdx.x;          // b*1024 + i : one block per output row
  const int i   = bi & (H - 1);
  const int b   = bi >> 10;

  // --- i weights (uniform per block): gi0 = floor((i+0.5)/64 - 0.5) ---
  float fi  = (i + 0.5f) * (1.0f / 64.0f) - 0.5f;
  float fif = floorf(fi);
  int   gi0 = (int)fif;
  float ti  = fi - fif;
  float wi0 = 1.0f - ti, wi1 = ti;
  int gi0c = gi0 < 0 ? 0 : gi0;
  int gi1c = (gi0 + 1 > GH - 1) ? GH - 1 : gi0 + 1;

  // --- Phase 1: i-lerp the grid into the fp16 pair slab.
  // Source layout (b,c,gk,gi,gj); float4 along gj. Each value lands in up to
  // two pair records (as row-low of pair gk, as row-high of pair gk-1).
  const float* gb = grid + (size_t)b * (GC * GD * GH * GW);
  for (int s = tid; s < GC * GD * (GW / 4); s += 256) {
    int gq = s & 3;                    // gj quad
    int ck = s >> 2;                   // c*8 + gk
    int gk = ck & 7;
    int c  = ck >> 3;
    const float* rowbase = gb + (ck << 8);
    float4 v0 = *reinterpret_cast<const float4*>(rowbase + gi0c * GW + gq * 4);
    float4 v1 = *reinterpret_cast<const float4*>(rowbase + gi1c * GW + gq * 4);
    float vals[4] = {wi0 * v0.x + wi1 * v1.x, wi0 * v0.y + wi1 * v1.y,
                     wi0 * v0.z + wi1 * v1.z, wi0 * v0.w + wi1 * v1.w};
#pragma unroll
    for (int m = 0; m < 4; ++m) {
      __half hv = __float2half(vals[m]);
      int base = (gq * 4 + m) * GJS_H;
      if (gk < GD - 1) gI[base + gk * GPR + c] = hv;            // row-low of pair gk
      if (gk > 0)      gI[base + (gk - 1) * GPR + 12 + c] = hv; // row-high of pair gk-1
    }
  }
  __syncthreads();

  // --- Phase 2: one thread = 4 consecutive j-pixels (quad never straddles a
  // j-cell). 6 ds_read_b128 + 24 pk_fma per pixel.
  const int j0 = tid << 2;
  const float4 g4 = *reinterpret_cast<const float4*>(
      guide + ((size_t)b << 20) + (i << 10) + j0);
  const float gv[4] = {g4.x, g4.y, g4.z, g4.w};

  float fj  = (j0 + 0.5f) * (1.0f / 64.0f) - 0.5f;
  float fjf = floorf(fj);
  int   gj0 = (int)fjf;
  float tj0 = fj - fjf;
  int gj0c = gj0 < 0 ? 0 : gj0;
  int gj1c = (gj0 + 1 > GW - 1) ? GW - 1 : gj0 + 1;
  const int rj0 = gj0c * GJS_H;
  const int rj1 = gj1c * GJS_H;

  __half2 acc[4][6];
#pragma unroll
  for (int p = 0; p < 4; ++p)
#pragma unroll
    for (int t = 0; t < 6; ++t) acc[p][t] = __float2half2_rn(0.0f);

#pragma unroll
  for (int p = 0; p < 4; ++p) {
    float tj  = tj0 + p * (1.0f / 64.0f);
    float wj0 = 1.0f - tj, wj1 = tj;

    // k weights (smoothed lerp, exact per reference)
    float fk  = gv[p] * (float)GD - 0.5f;
    float fkf = floorf(fk);
    int   gk0 = (int)fkf;                  // in [-1, 7]
    float tk  = fk - fkf;
    float wk0 = fmaxf(1.0f - sqrtf(tk * tk + 1e-8f), 0.0f);
    float uk  = 1.0f - tk;
    float wk1 = fmaxf(1.0f - sqrtf(uk * uk + 1e-8f), 0.0f);

    // clamp folded into pair weights: pair r covers rows (r, r+1)
    bool lo = gk0 < 0, hi = gk0 > GD - 2;
    int  r  = lo ? 0 : (hi ? GD - 2 : gk0);
    float a0 = lo ? wk0 + wk1 : (hi ? 0.0f : wk0);
    float a1 = hi ? wk0 + wk1 : (lo ? 0.0f : wk1);

    __half2 b00 = __float2half2_rn(wj0 * a0);
    __half2 b01 = __float2half2_rn(wj0 * a1);
    __half2 b10 = __float2half2_rn(wj1 * a0);
    __half2 b11 = __float2half2_rn(wj1 * a1);

    int off = r * GPR;
    accum_rec(gI, rj0 + off, b00, b01, acc[p]);
    accum_rec(gI, rj1 + off, b10, b11, acc[p]);
  }

  // --- epilogue: unpack once, store out[b][c][i][j0..j0+3] as float4 ---
  float* ob = out + (((size_t)b * GC) << 20) + (i << 10) + j0;
#pragma unroll
  for (int c2 = 0; c2 < 6; ++c2) {
    float2 f0 = __half22float2(acc[0][c2]);
    float2 f1 = __half22float2(acc[1][c2]);
    float2 f2 = __half22float2(acc[2][c2]);
    float2 f3 = __half22float2(acc[3][c2]);
    float4 vlo = make_float4(f0.x, f1.x, f2.x, f3.x);   // channel 2*c2
    float4 vhi = make_float4(f0.y, f1.y, f2.y, f3.y);   // channel 2*c2+1
    *reinterpret_cast<float4*>(ob + ((size_t)(2 * c2) << 20))     = vlo;
    *reinterpret_cast<float4*>(ob + ((size_t)(2 * c2 + 1) << 20)) = vhi;
  }
}

extern "C" void kernel_launch(void* const* d_in, const int* in_sizes, int n_in,
                              void* d_out, int out_size, void* d_ws, size_t ws_size,
                              hipStream_t stream) {
  const float* grid  = (const float*)d_in[0];   // (2,12,8,16,16) fp32
  const float* guide = (const float*)d_in[1];   // (2,1,1024,1024) fp32
  float* out = (float*)d_out;                   // (2,12,1024,1024) fp32

  const int nblocks = NB * H;                   // one block per (b, i) row
  slice_fused_k<<<nblocks, 256, 0, stream>>>(grid, guide, out);
}

// Round 5
// 24.482 us; speedup vs baseline: 1.7597x; 1.0223x over previous
//
#include <hip/hip_runtime.h>
#include <hip/hip_fp16.h>

#define GH 16
#define GW 16
#define GD 8
#define GC 12
#define H 1024
#define W 1024
#define NB 2

#define ROWS 4                    // rows per persistent block
#define TPB 512                   // threads per block (2 px/thread)

// LDS slab: i-pre-reduced grid, fp16, k-PAIR records.
// gI[gj][r][0..23]: halfs [0..11] = row gk=r ch 0..11, halfs [12..23] = row
// gk=r+1 ch 0..11, r in [0,6]. Pair record 48 B, 16B-aligned; gj stride 176
// halfs (352 B) rotates banks so the 4 gj-groups of a wave rarely collide.
#define GPR 24
#define NPAIR (GD - 1)
#define GJS_H (NPAIR * GPR + 8)   // 176 halfs per gj
#define LDS_HALFS (GW * GJS_H)    // 2816 halfs = 5632 B

// One 48B pair record (rows r,r+1 of one gj) -> 6 half2 accumulators.
__device__ inline void accum_rec(const __half* __restrict__ buf, int off,
                                 __half2 b0, __half2 b1, __half2* __restrict__ acc) {
  union U { uint4 u; __half2 h[4]; };
  const uint4* p = reinterpret_cast<const uint4*>(buf + off);
  U qa, qb, qc;
  qa.u = p[0]; qb.u = p[1]; qc.u = p[2];
  acc[0] = __hfma2(b0, qa.h[0], acc[0]);
  acc[1] = __hfma2(b0, qa.h[1], acc[1]);
  acc[2] = __hfma2(b0, qa.h[2], acc[2]);
  acc[3] = __hfma2(b0, qa.h[3], acc[3]);
  acc[4] = __hfma2(b0, qb.h[0], acc[4]);
  acc[5] = __hfma2(b0, qb.h[1], acc[5]);
  acc[0] = __hfma2(b1, qb.h[2], acc[0]);
  acc[1] = __hfma2(b1, qb.h[3], acc[1]);
  acc[2] = __hfma2(b1, qc.h[0], acc[2]);
  acc[3] = __hfma2(b1, qc.h[1], acc[3]);
  acc[4] = __hfma2(b1, qc.h[2], acc[4]);
  acc[5] = __hfma2(b1, qc.h[3], acc[5]);
}

// i-weights for global row index i (uniform per block at each iteration).
__device__ inline void i_weights(int i, float& wi0, float& wi1, int& gi0c, int& gi1c) {
  float fi  = (i + 0.5f) * (1.0f / 64.0f) - 0.5f;
  float fif = floorf(fi);
  int   gi0 = (int)fif;
  float ti  = fi - fif;
  wi0 = 1.0f - ti; wi1 = ti;
  gi0c = gi0 < 0 ? 0 : gi0;
  gi1c = (gi0 + 1 > GH - 1) ? GH - 1 : gi0 + 1;
}

// Phase-1 staged write: slot tid<384 covers (c,k,gj-quad); v0/v1 are the two
// gi-plane float4s already in registers.
__device__ inline void slab_write(__half* __restrict__ buf, int gq, int ck,
                                  float wi0, float wi1, float4 v0, float4 v1) {
  int gk = ck & 7;
  int c  = ck >> 3;
  float vals[4] = {wi0 * v0.x + wi1 * v1.x, wi0 * v0.y + wi1 * v1.y,
                   wi0 * v0.z + wi1 * v1.z, wi0 * v0.w + wi1 * v1.w};
#pragma unroll
  for (int m = 0; m < 4; ++m) {
    __half hv = __float2half(vals[m]);
    int base = (gq * 4 + m) * GJS_H;
    if (gk < GD - 1) buf[base + gk * GPR + c] = hv;            // row-low of pair gk
    if (gk > 0)      buf[base + (gk - 1) * GPR + 12 + c] = hv; // row-high of pair gk-1
  }
}

__global__ __launch_bounds__(TPB, 4) void slice_pipe_k(const float* __restrict__ grid,
                                                       const float* __restrict__ guide,
                                                       float* __restrict__ out) {
  __shared__ __half gI[2][LDS_HALFS];

  const int tid = threadIdx.x;
  const int r0  = blockIdx.x * ROWS;     // global row id base (= b*1024 + i0)
  const int b   = r0 >> 10;              // ROWS divides 1024: b uniform
  const int j0  = tid << 1;              // 2 px per thread

  const float* gb      = grid + (size_t)b * (GC * GD * GH * GW);
  const float* guide_b = guide + ((size_t)b << 20);

  // --- j cell (constant for this thread across all rows) ---
  float fj  = (j0 + 0.5f) * (1.0f / 64.0f) - 0.5f;
  float fjf = floorf(fj);
  int   gj0 = (int)fjf;
  float tj0 = fj - fjf;
  int gj0c = gj0 < 0 ? 0 : gj0;
  int gj1c = (gj0 + 1 > GW - 1) ? GW - 1 : gj0 + 1;
  const int rj0 = gj0c * GJS_H;
  const int rj1 = gj1c * GJS_H;

  // phase-1 slot for this thread (slots 0..383)
  const bool p1 = tid < GC * GD * (GW / 4);
  const int  gq = tid & 3;
  const int  ck = tid >> 2;
  const float* rowbase = gb + (ck << 8);

  // --- prologue: stage row r0 ---
  float wi0, wi1; int gi0c, gi1c;
  i_weights(r0 & (H - 1), wi0, wi1, gi0c, gi1c);
  float4 v0 = {}, v1 = {};
  if (p1) {
    v0 = *reinterpret_cast<const float4*>(rowbase + gi0c * GW + gq * 4);
    v1 = *reinterpret_cast<const float4*>(rowbase + gi1c * GW + gq * 4);
  }
  float2 g_cur = *reinterpret_cast<const float2*>(guide_b + ((r0 & (H - 1)) << 10) + j0);
  if (p1) slab_write(gI[0], gq, ck, wi0, wi1, v0, v1);
  __syncthreads();

  int cur = 0;
#pragma unroll
  for (int r = 0; r < ROWS; ++r) {
    const int i = (r0 + r) & (H - 1);
    const bool has_next = (r + 1 < ROWS);

    // (1) issue next row's loads early — latency hides under phase 2
    float4 nv0 = {}, nv1 = {};
    float2 g_nxt = {};
    float nwi0 = 0.f, nwi1 = 0.f;
    if (has_next) {
      int i_n = (r0 + r + 1) & (H - 1);
      int ngi0c, ngi1c;
      i_weights(i_n, nwi0, nwi1, ngi0c, ngi1c);
      if (p1) {
        nv0 = *reinterpret_cast<const float4*>(rowbase + ngi0c * GW + gq * 4);
        nv1 = *reinterpret_cast<const float4*>(rowbase + ngi1c * GW + gq * 4);
      }
      g_nxt = *reinterpret_cast<const float2*>(guide_b + (i_n << 10) + j0);
    }

    // (2) phase 2: 2 pixels from slab buffer `cur`
    const __half* buf = gI[cur];
    __half2 acc[2][6];
#pragma unroll
    for (int p = 0; p < 2; ++p)
#pragma unroll
      for (int t = 0; t < 6; ++t) acc[p][t] = __float2half2_rn(0.0f);

    const float gvv[2] = {g_cur.x, g_cur.y};
#pragma unroll
    for (int p = 0; p < 2; ++p) {
      float tj  = tj0 + p * (1.0f / 64.0f);
      float wj0 = 1.0f - tj, wj1 = tj;

      float fk  = gvv[p] * (float)GD - 0.5f;
      float fkf = floorf(fk);
      int   gk0 = (int)fkf;                  // in [-1, 7]
      float tk  = fk - fkf;
      float wk0 = fmaxf(1.0f - sqrtf(tk * tk + 1e-8f), 0.0f);
      float uk  = 1.0f - tk;
      float wk1 = fmaxf(1.0f - sqrtf(uk * uk + 1e-8f), 0.0f);

      bool lo = gk0 < 0, hi = gk0 > GD - 2;
      int  rr = lo ? 0 : (hi ? GD - 2 : gk0);
      float a0 = lo ? wk0 + wk1 : (hi ? 0.0f : wk0);
      float a1 = hi ? wk0 + wk1 : (lo ? 0.0f : wk1);

      __half2 b00 = __float2half2_rn(wj0 * a0);
      __half2 b01 = __float2half2_rn(wj0 * a1);
      __half2 b10 = __float2half2_rn(wj1 * a0);
      __half2 b11 = __float2half2_rn(wj1 * a1);

      int off = rr * GPR;
      accum_rec(buf, rj0 + off, b00, b01, acc[p]);
      accum_rec(buf, rj1 + off, b10, b11, acc[p]);
    }

    // stores: out[b][c][i][j0..j0+1], float2 per channel
    float* ob = out + (((size_t)b * GC) << 20) + ((size_t)i << 10) + j0;
#pragma unroll
    for (int c2 = 0; c2 < 6; ++c2) {
      float2 f0 = __half22float2(acc[0][c2]);
      float2 f1 = __half22float2(acc[1][c2]);
      *reinterpret_cast<float2*>(ob + ((size_t)(2 * c2) << 20)) = make_float2(f0.x, f1.x);
      *reinterpret_cast<float2*>(ob + ((size_t)(2 * c2 + 1) << 20)) = make_float2(f0.y, f1.y);
    }

    // (3) write-late: next slab into the other buffer, then one barrier
    if (has_next) {
      if (p1) slab_write(gI[cur ^ 1], gq, ck, nwi0, nwi1, nv0, nv1);
      g_cur = g_nxt;
      __syncthreads();
      cur ^= 1;
    }
  }
}

extern "C" void kernel_launch(void* const* d_in, const int* in_sizes, int n_in,
                              void* d_out, int out_size, void* d_ws, size_t ws_size,
                              hipStream_t stream) {
  const float* grid  = (const float*)d_in[0];   // (2,12,8,16,16) fp32
  const float* guide = (const float*)d_in[1];   // (2,1,1024,1024) fp32
  float* out = (float*)d_out;                   // (2,12,1024,1024) fp32

  const int nblocks = NB * H / ROWS;            // 512 blocks = 2 per CU, resident
  slice_pipe_k<<<nblocks, TPB, 0, stream>>>(grid, guide, out);
}